// Round 1
// baseline (394.004 us; speedup 1.0000x reference)
//
#include <hip/hip_runtime.h>
#include <math.h>

#define MAXDEG 20
#define NM 21               // m = 0..20
#define RANK 256
#define PPB 12              // points per block
#define NSLOT (2*PPB)       // 24 (point,dir) table slots
#define S_STRIDE 446        // words per slot: even (b64 align), 446%32=30
#define HDRS 65             // header stride (odd -> no bank conflicts on pd-parallel reads)

// Storage layout inside a slot (441 used words of S_STRIDE):
//   m=1..20 pair-columns first: base cb(m) = (m-1)*(42-m) (always even),
//     entry for l (l=m..20): [cb + 2*(l-m)] = Y_{l,+m}, [cb + 2*(l-m)+1] = Y_{l,-m}
//   m=0 column at [420 + l], l=0..20.

__device__ __forceinline__ int remap_idx(int k) {
  // flax index k = l*(l+1)+m  ->  storage index
  int l = (int)sqrtf((float)k);
  if (l*l > k) --l;
  if ((l+1)*(l+1) <= k) ++l;
  int m = k - l*(l+1);
  int am = m < 0 ? -m : m;
  if (am == 0) return 420 + l;
  return (am-1)*(42-am) + 2*(l-am) + (m < 0 ? 1 : 0);
}

__global__ __launch_bounds__(256, 3)
void sh_fused(const float* __restrict__ coords,
              const int* __restrict__ rand_i,
              const int* __restrict__ rand_j,
              float* __restrict__ out, int N) {
  __shared__ float2 s_ab[231];              // normalized-recurrence coeffs (a,b) per tri(l,m)
  __shared__ float  s_hdr[NSLOT * HDRS];    // per (p,d): [0..20]=cos(m phi) [21..41]=sin [42..62]=Pmm seeds [63]=x
  __shared__ float  s_tab[NSLOT * S_STRIDE];

  const int t  = threadIdx.x;
  const int n0 = blockIdx.x * PPB;

  // ---- remap gather indices (once, registers) ----
  const int ri = remap_idx(rand_i[t]);
  const int rj = remap_idx(rand_j[t]);

  // ---- phase 0a: coefficient table. tri index t -> (l,m) ----
  if (t < 231) {
    int l = (int)((sqrtf(8.0f*(float)t + 1.0f) - 1.0f) * 0.5f);
    if (l*(l+1)/2 > t) --l;
    if ((l+1)*(l+2)/2 <= t) ++l;
    int m = t - l*(l+1)/2;
    float a = 0.f, b = 0.f;
    if (l >= m + 2) {
      float l2 = (float)(l*l), m2 = (float)(m*m);
      float inv = 1.0f / (l2 - m2);
      a = sqrtf((4.f*l2 - 1.f) * inv);
      b = sqrtf((2.f*(float)l + 1.f) * ((float)((l-1)*(l-1)) - m2)
                / (2.f*(float)l - 3.f) * inv);
    }
    s_ab[t] = make_float2(a, b);
  }

  // ---- phase 0b: per-(point,dir) header ----
  if (t < NSLOT) {
    int p = t >> 1, d = t & 1;
    int n = n0 + p; if (n >= N) n = N - 1;
    const float* c = coords + (size_t)n * 6 + d * 3;
    float cx = c[0], cy = c[1], cz = c[2];
    float r2 = cx*cx + cy*cy + cz*cz;
    float x = cz * rsqrtf(r2);                 // cos(inclination)
    x = fminf(1.f, fmaxf(-1.f, x));
    float s = sqrtf(fmaxf(0.f, 1.f - x*x));    // sin(inclination) >= 0
    float rho2 = cx*cx + cy*cy;
    float cphi, sphi;
    if (rho2 > 0.f) { float ir = rsqrtf(rho2); cphi = cx*ir; sphi = cy*ir; }
    else            { cphi = 1.f; sphi = 0.f; }   // atan2(0,0)=0 convention
    float* h = s_hdr + t * HDRS;
    float cm = 1.f, sm = 0.f;
    float pmm = 0.28209479177387814f;          // sqrt(1/(4*pi)) = Pbar_00
    h[0] = 1.f; h[21] = 0.f; h[42] = pmm; h[63] = x;
    for (int m = 1; m <= MAXDEG; ++m) {
      float cn = cm*cphi - sm*sphi;            // incremental rotation -> cos/sin(m phi)
      float sn = sm*cphi + cm*sphi;
      cm = cn; sm = sn;
      float df = -sqrtf((2.f*(float)m + 1.f) / (2.f*(float)m));  // CS phase
      if (m == 1) df *= 1.41421356237309515f;  // fold sqrt(2) for all m>=1
      pmm = df * s * pmm;
      h[m] = cm; h[21+m] = sm; h[42+m] = pmm;
    }
  }
  __syncthreads();

  // ---- phase 1: fill Y tables. tasks sorted by m => low trip-count divergence ----
  for (int task = t; task < NM * NSLOT; task += 256) {
    int m  = task / NSLOT;          // major = m (sorted)
    int pd = task - m * NSLOT;
    const float* h = s_hdr + pd * HDRS;
    float x  = h[63];
    float cm = h[m], sm = h[21+m], p1 = h[42+m];
    float* slot = s_tab + pd * S_STRIDE;
    if (m == 0) {
      float* col = slot + 420;
      col[0] = p1;                             // Y_00
      float p2 = p1;
      float p = 1.7320508075688772f * x * p1;  // sqrt(3)*x*Pbar00 = Y_10
      col[1] = p;
      int ti = 3;                              // tri(2,0)
      for (int l = 2; l <= MAXDEG; ++l) {
        float2 ab = s_ab[ti];
        float pn = ab.x * (x * p) - ab.y * p2;
        p2 = p; p = pn;
        col[l] = pn;
        ti += l + 1;
      }
    } else {
      float2* col = (float2*)(slot + (m-1)*(42-m));
      col[0] = make_float2(p1*cm, p1*sm);      // l = m
      if (m < MAXDEG) {
        float p2 = p1;
        float p = sqrtf(2.f*(float)m + 3.f) * x * p1;   // l = m+1
        col[1] = make_float2(p*cm, p*sm);
        int ti = (m+2)*(m+3)/2 + m;            // tri(m+2, m)
        for (int l = m+2; l <= MAXDEG; ++l) {
          float2 ab = s_ab[ti];
          float pn = ab.x * (x * p) - ab.y * p2;
          p2 = p; p = pn;
          col[l-m] = make_float2(pn*cm, pn*sm);
          ti += l + 1;
        }
      }
    }
  }
  __syncthreads();

  // ---- phase 2: gathered products, coalesced store (thread t = rank t) ----
  for (int p = 0; p < PPB; ++p) {
    int n = n0 + p;
    if (n < N) {
      float v = s_tab[(2*p)*S_STRIDE + ri] * s_tab[(2*p+1)*S_STRIDE + rj];
      out[(size_t)n * RANK + t] = v;
    }
  }
}

extern "C" void kernel_launch(void* const* d_in, const int* in_sizes, int n_in,
                              void* d_out, int out_size, void* d_ws, size_t ws_size,
                              hipStream_t stream) {
  const float* coords = (const float*)d_in[0];
  const int*   rand_i = (const int*)d_in[1];
  const int*   rand_j = (const int*)d_in[2];
  float*       out    = (float*)d_out;
  const int N = in_sizes[0] / 6;
  const int grid = (N + PPB - 1) / PPB;
  sh_fused<<<grid, 256, 0, stream>>>(coords, rand_i, rand_j, out, N);
}